// Round 6
// baseline (1948.711 us; speedup 1.0000x reference)
//
#include <hip/hip_runtime.h>

typedef unsigned short bhalf;          // bf16 bits
typedef __attribute__((ext_vector_type(4))) float    f32x4;
typedef __attribute__((ext_vector_type(8))) short    s16x8;
typedef __attribute__((ext_vector_type(4))) float    floatx4;
typedef __attribute__((ext_vector_type(4))) unsigned short u16x4;

#define B_  2
#define S_  2048
#define HID_ 2048
#define NH_ 16
#define HD_ 128
#define M_  (B_*S_)          // 4096
#define MASKV (-10000.0f)

__device__ __forceinline__ bhalf f32_to_bf16(float f) {
    union { float f; unsigned int u; } v; v.f = f;
    unsigned int r = v.u + 0x7FFFu + ((v.u >> 16) & 1u);   // RNE
    return (bhalf)(r >> 16);
}
__device__ __forceinline__ bhalf f32_to_bf16_trunc(float f) {
    union { float f; unsigned int u; } v; v.f = f;
    return (bhalf)(v.u >> 16);
}

// async global->LDS, 16B per lane; LDS dest = wave-uniform base + lane*16
__device__ __forceinline__ void gl_lds16(const void* g, void* l) {
    __builtin_amdgcn_global_load_lds(
        (const __attribute__((address_space(1))) void*)g,
        (__attribute__((address_space(3))) void*)l, 16, 0, 0);
}

// ---------------- fused cast fp32 -> bf16 for hs + Wq + Wk + Wv ------------
__global__ __launch_bounds__(256) void cast_all(const float* __restrict__ hs,
                                                const float* __restrict__ Wq,
                                                const float* __restrict__ Wk,
                                                const float* __restrict__ Wv,
                                                bhalf* __restrict__ dst) {
    int idx = blockIdx.x * 256 + threadIdx.x;           // 0 .. 5,242,879
    const float* src;
    if (idx < 2097152)      src = hs + (size_t)idx * 4;
    else if (idx < 3145728) src = Wq + (size_t)(idx - 2097152) * 4;
    else if (idx < 4194304) src = Wk + (size_t)(idx - 3145728) * 4;
    else                    src = Wv + (size_t)(idx - 4194304) * 4;
    floatx4 f = *(const floatx4*)src;
    u16x4 o;
    o.x = f32_to_bf16(f.x); o.y = f32_to_bf16(f.y);
    o.z = f32_to_bf16(f.z); o.w = f32_to_bf16(f.w);
    *(u16x4*)(dst + (size_t)idx * 4) = o;
}

// ---------------- RoPE table -----------------------------------------------
__global__ __launch_bounds__(256) void rope_table(float2* __restrict__ tab) {
    int idx = blockIdx.x * 256 + threadIdx.x;   // 65536 = 2048 s x 32 i
    int i = idx & 31, s = idx >> 5;
    float inv = expf(-(float)i * 0.2878231366242557f);   // ln(10000)/32
    float ang = (float)s * inv;
    tab[idx] = make_float2(sinf(ang), cosf(ang));
}

// ---------------- fused QKV GEMM, BK=64, RoPE fused in epilogue ------------
// z==2 (V) writes V^T directly: VT[((b*16+h)*128+d)*2048 + s]
// z<2: wx==0 waves (cols 0..63 of each head) apply RoPE via shfl_xor pairing.
__global__ __launch_bounds__(256) void qkv_gemm(const bhalf* __restrict__ A,
                                                const bhalf* __restrict__ Wb,
                                                const float* __restrict__ bq,
                                                const float* __restrict__ bk,
                                                const float* __restrict__ bv,
                                                const float2* __restrict__ tab,
                                                bhalf* __restrict__ Out,
                                                bhalf* __restrict__ VTo) {
    __shared__ __align__(16) bhalf As[128 * 64];
    __shared__ __align__(16) bhalf Bs[128 * 64];
    const int tid  = threadIdx.x;
    const int lane = tid & 63, w = tid >> 6;
    const int wy = w >> 1, wx = w & 1;
    const int quad = lane >> 4, l = lane & 15;
    const int m0 = blockIdx.x * 128, n0 = blockIdx.y * 128;
    const int z  = blockIdx.z;
    const bhalf* W    = Wb + (size_t)z * HID_ * HID_;
    const float* bias = (z == 0) ? bq : (z == 1) ? bk : bv;
    bhalf* out        = Out + (size_t)z * M_ * HID_;

    f32x4 acc[4][4] = {};

    for (int kt = 0; kt < HID_; kt += 64) {
#pragma unroll
        for (int j = 0; j < 4; ++j) {
            int slot0 = j * 256 + w * 64;          // wave-uniform
            int slot  = slot0 + lane;
            int row = slot >> 3;
            int cg  = (slot & 7) ^ (row & 7);      // 3-bit swizzle
            gl_lds16(A + (size_t)(m0 + row) * HID_ + kt + cg * 8, As + slot0 * 8);
            gl_lds16(W + (size_t)(n0 + row) * HID_ + kt + cg * 8, Bs + slot0 * 8);
        }
        __syncthreads();
        s16x8 af[4][2], bfr[4][2];
#pragma unroll
        for (int mt = 0; mt < 4; ++mt) {
            int row = wy * 64 + mt * 16 + l;
#pragma unroll
            for (int ks = 0; ks < 2; ++ks) {
                int kk = ks * 4 + quad;
                af[mt][ks] = *(const s16x8*)(As + (row * 8 + (kk ^ (row & 7))) * 8);
            }
        }
#pragma unroll
        for (int nt = 0; nt < 4; ++nt) {
            int row = wx * 64 + nt * 16 + l;
#pragma unroll
            for (int ks = 0; ks < 2; ++ks) {
                int kk = ks * 4 + quad;
                bfr[nt][ks] = *(const s16x8*)(Bs + (row * 8 + (kk ^ (row & 7))) * 8);
            }
        }
#pragma unroll
        for (int ks = 0; ks < 2; ++ks)
#pragma unroll
            for (int mt = 0; mt < 4; ++mt)
#pragma unroll
                for (int nt = 0; nt < 4; ++nt)
                    acc[mt][nt] = __builtin_amdgcn_mfma_f32_16x16x32_bf16(
                        af[mt][ks], bfr[nt][ks], acc[mt][nt], 0, 0, 0);
        __syncthreads();
    }
    if (z == 2) {
        // V^T epilogue: pack 4 consecutive s into one 8B store
#pragma unroll
        for (int mt = 0; mt < 4; ++mt) {
#pragma unroll
            for (int nt = 0; nt < 4; ++nt) {
                int col = n0 + wx * 64 + nt * 16 + l;     // h*128 + d
                float bv_ = bias[col];
                int row0 = m0 + wy * 64 + mt * 16 + quad * 4;  // = b*2048 + s0
                int bb = row0 >> 11, s0 = row0 & 2047;
                u16x4 o;
#pragma unroll
                for (int r = 0; r < 4; ++r) o[r] = f32_to_bf16(acc[mt][nt][r] + bv_);
                *(u16x4*)(VTo + ((size_t)(bb * 16) * 128 + col) * S_ + s0) = o;
            }
        }
    } else if (wx == 0) {
        // rotary region (cols 0..63 of each head): RoPE via lane-pair exchange
#pragma unroll
        for (int mt = 0; mt < 4; ++mt) {
#pragma unroll
            for (int nt = 0; nt < 4; ++nt) {
                int col = n0 + nt * 16 + l;
                float bv_ = bias[col];
                int i = (nt * 16 + l) >> 1;                // rotary pair index
#pragma unroll
                for (int r = 0; r < 4; ++r) {
                    int row = m0 + wy * 64 + mt * 16 + quad * 4 + r;
                    float v  = acc[mt][nt][r] + bv_;
                    float vp = __shfl_xor(v, 1, 64);       // partner col^1
                    float2 sc = tab[(row & 2047) * 32 + i];
                    float y = (l & 1) ? (v * sc.y + vp * sc.x)
                                      : (v * sc.y - vp * sc.x);
                    out[(size_t)row * HID_ + col] = f32_to_bf16(y);
                }
            }
        }
    } else {
#pragma unroll
        for (int mt = 0; mt < 4; ++mt) {
#pragma unroll
            for (int nt = 0; nt < 4; ++nt) {
                int col = n0 + 64 + nt * 16 + l;
                float bv_ = bias[col];
#pragma unroll
                for (int r = 0; r < 4; ++r) {
                    int row = m0 + wy * 64 + mt * 16 + quad * 4 + r;
                    out[(size_t)row * HID_ + col] = f32_to_bf16(acc[mt][nt][r] + bv_);
                }
            }
        }
    }
}

// ---------------- flash attention v3 ---------------------------------------
// Grid (8,32) = 256 blocks = 1/CU. Block p: hi tile = 128 rows at (15-p)*128,
// lo tile = 128 rows at p*128. Wave w owns 16 rows of EACH tile; K/V
// fragments feed both (2 MFMAs per ds_read). 128-key chunks, two 64-key
// softmax passes (caps score VGPRs at 32). K dbuf; V single-buffer staged
// behind QK (vmcnt(4) mid-wait); dedicated per-wave P regions.
__device__ __forceinline__ void softmax4(const f32x4* sc, float* m_run, f32x4& l_acc,
        f32x4* accO, bhalf* Pw, int row_base, bool diag, int keybase,
        const float* am, int quad, int l) {
#pragma unroll
    for (int r = 0; r < 4; ++r) {
        const int qrow = row_base + quad * 4 + r;
        float p[4];
#pragma unroll
        for (int nt = 0; nt < 4; ++nt) {
            float v = sc[nt][r] * 0.08838834764831845f;   // 1/sqrt(128)
            if (diag) { int key = keybase + nt * 16 + l; v = (key > qrow) ? MASKV : v; }
            p[nt] = v + am[nt];
        }
        float mx = fmaxf(fmaxf(p[0], p[1]), fmaxf(p[2], p[3]));
#pragma unroll
        for (int msk = 1; msk < 16; msk <<= 1) mx = fmaxf(mx, __shfl_xor(mx, msk, 64));
        float m_new = fmaxf(m_run[r], mx);
        float alpha = __expf(m_run[r] - m_new);
        m_run[r] = m_new;
        const int m  = quad * 4 + r;
        const int fm = (quad << 1) | (r & 1);
#pragma unroll
        for (int nt = 0; nt < 4; ++nt) {
            float e = __expf(p[nt] - m_new);
            int kl = nt * 16 + l;                         // local key 0..63
            Pw[(m * 8 + ((kl >> 3) ^ fm)) * 8 + (kl & 7)] = f32_to_bf16_trunc(e);
        }
        l_acc[r] *= alpha;
#pragma unroll
        for (int nt = 0; nt < 8; ++nt) accO[nt][r] *= alpha;
    }
}

__global__ __launch_bounds__(512, 2) void flash_attn(const bhalf* __restrict__ Qb,
                                                     const bhalf* __restrict__ Kb,
                                                     const bhalf* __restrict__ VT,
                                                     const float* __restrict__ amask,
                                                     float* __restrict__ out) {
    __shared__ __align__(16) bhalf Kbuf[2][2048 * 8];   // 2 x 32KB
    __shared__ __align__(16) bhalf Vbuf[2048 * 8];      // 32KB
    __shared__ __align__(16) bhalf Ps[8][2][1024];      // 32KB: wave x {hi,lo} x 16x64
    const int tid = threadIdx.x, lane = tid & 63, w = tid >> 6;   // w 0..7
    const int quad = lane >> 4, l = lane & 15;
    const int p = blockIdx.x, bh = blockIdx.y;
    const int b = bh >> 4, h = bh & 15;
    const int row_hi = (15 - p) * 128 + w * 16;
    const int row_lo = p * 128 + w * 16;
    const int ch = 16 - p;                       // 128-key chunks for hi tile

    // Q A-fragments: A[m=l][k=ks*32+quad*8+j]
    s16x8 qfh[4], qfl[4];
    {
        const bhalf* Qh = Qb + (size_t)(b * S_ + row_hi + l) * HID_ + h * HD_;
        const bhalf* Ql = Qb + (size_t)(b * S_ + row_lo + l) * HID_ + h * HD_;
#pragma unroll
        for (int ks = 0; ks < 4; ++ks) {
            qfh[ks] = *(const s16x8*)(Qh + ks * 32 + quad * 8);
            qfl[ks] = *(const s16x8*)(Ql + ks * 32 + quad * 8);
        }
    }
    s16x8 ones;
#pragma unroll
    for (int j = 0; j < 8; ++j) ones[j] = (short)0x3F80;

    float mh[4] = {-1e30f, -1e30f, -1e30f, -1e30f};
    float ml[4] = {-1e30f, -1e30f, -1e30f, -1e30f};
    f32x4 lh = {}, lvl = {};
    f32x4 ah[8] = {}, al[8] = {};
    bhalf* Ph = &Ps[w][0][0];
    bhalf* Pl = &Ps[w][1][0];
    const int fpl = ((l >> 2) << 1) | (l & 1);   // fp(m=l) for P reads

    // ---- prologue: stage K chunk 0 into Kbuf[0] ----
#pragma unroll
    for (int j = 0; j < 4; ++j) {
        int slot0 = w * 256 + j * 64;            // wave-uniform
        int slot  = slot0 + lane;
        int key = slot >> 4, x = slot & 15;
        int g   = (x & 8) | ((x ^ key) & 7);
        gl_lds16(Kb + (size_t)(b * S_ + key) * HID_ + h * HD_ + g * 8,
                 &Kbuf[0][slot0 * 8]);
    }

    for (int kc = 0; kc < ch; ++kc) {
        const int cur = kc & 1, nxt = cur ^ 1;
        const int key0 = kc * 128;
        // entry: K(kc) resident, all prior V/P reads done
        __asm__ __volatile__("s_waitcnt vmcnt(0)\n\ts_barrier" ::: "memory");

        const bool lo_act = (kc <= p);
        const bool dgh = (kc == ch - 1), dgl = (kc == p);
        float am[8];
#pragma unroll
        for (int nt = 0; nt < 8; ++nt) am[nt] = amask[b * S_ + key0 + nt * 16 + l];

        // issue V(kc) staging (oldest), then K(kc+1)
#pragma unroll
        for (int j = 0; j < 4; ++j) {
            int slot0 = w * 256 + j * 64;
            int slot  = slot0 + lane;
            int d = slot >> 4, x = slot & 15;
            int g = (x & 8) | ((x ^ d) & 7);
            gl_lds16(VT + ((size_t)bh * HD_ + d) * S_ + key0 + g * 8,
                     &Vbuf[slot0 * 8]);
        }
        const bool hasK = (kc + 1 < ch);
        if (hasK) {
            const int key1 = key0 + 128;
#pragma unroll
            for (int j = 0; j < 4; ++j) {
                int slot0 = w * 256 + j * 64;
                int slot  = slot0 + lane;
                int key = slot >> 4, x = slot & 15;
                int g   = (x & 8) | ((x ^ key) & 7);
                gl_lds16(Kb + (size_t)(b * S_ + key1 + key) * HID_ + h * HD_ + g * 8,
                         &Kbuf[nxt][slot0 * 8]);
            }
        }
        const bhalf* Kc = &Kbuf[cur][0];

#pragma unroll
        for (int pass = 0; pass < 2; ++pass) {
            // ---- QK^T: 64 keys, kf shared by hi+lo ----
            f32x4 sh4[4] = {}, sl4[4] = {};
#pragma unroll
            for (int nt = 0; nt < 4; ++nt) {
                int key = pass * 64 + nt * 16 + l;
#pragma unroll
                for (int ks = 0; ks < 4; ++ks) {
                    int dg = ks * 4 + quad;
                    int x  = (dg & 8) | ((dg ^ key) & 7);
                    s16x8 kf = *(const s16x8*)(Kc + (key * 16 + x) * 8);
                    sh4[nt] = __builtin_amdgcn_mfma_f32_16x16x32_bf16(qfh[ks], kf, sh4[nt], 0, 0, 0);
                    if (lo_act)
                        sl4[nt] = __builtin_amdgcn_mfma_f32_16x16x32_bf16(qfl[ks], kf, sl4[nt], 0, 0, 0);
                }
            }
            // ---- softmax + P writes (wave-private regions) ----
            softmax4(sh4, mh, lh, ah, Ph, row_hi, dgh, key0 + pass * 64, am + pass * 4, quad, l);
            if (lo_act)
                softmax4(sl4, ml, lvl, al, Pl, row_lo, dgl, key0 + pass * 64, am + pass * 4, quad, l);

            if (pass == 0) {   // V(kc) must be resident before first PV
                if (hasK) __asm__ __volatile__("s_waitcnt vmcnt(4)\n\ts_barrier" ::: "memory");
                else      __asm__ __volatile__("s_waitcnt vmcnt(0)\n\ts_barrier" ::: "memory");
            }
            // ---- PV: vf shared by hi+lo ----
#pragma unroll
            for (int kstep = 0; kstep < 2; ++kstep) {
                int kgl = kstep * 4 + quad;              // local key group 0..7
                int kg  = pass * 8 + kgl;                // global key group 0..15
                s16x8 pfh = *(const s16x8*)(Ph + (l * 8 + (kgl ^ fpl)) * 8);
                lh = __builtin_amdgcn_mfma_f32_16x16x32_bf16(pfh, ones, lh, 0, 0, 0);
                s16x8 pfl;
                if (lo_act) {
                    pfl = *(const s16x8*)(Pl + (l * 8 + (kgl ^ fpl)) * 8);
                    lvl = __builtin_amdgcn_mfma_f32_16x16x32_bf16(pfl, ones, lvl, 0, 0, 0);
                }
#pragma unroll
                for (int nt = 0; nt < 8; ++nt) {
                    int d = nt * 16 + l;
                    int x = (kg & 8) | ((kg ^ d) & 7);
                    s16x8 vf = *(const s16x8*)(Vbuf + (d * 16 + x) * 8);
                    ah[nt] = __builtin_amdgcn_mfma_f32_16x16x32_bf16(pfh, vf, ah[nt], 0, 0, 0);
                    if (lo_act)
                        al[nt] = __builtin_amdgcn_mfma_f32_16x16x32_bf16(pfl, vf, al[nt], 0, 0, 0);
                }
            }
        }
    }

    // ---- epilogue: O /= l, fp32 out (B,S,HID) ----
    float ih[4], il[4];
#pragma unroll
    for (int r = 0; r < 4; ++r) { ih[r] = 1.f / lh[r]; il[r] = 1.f / lvl[r]; }
#pragma unroll
    for (int nt = 0; nt < 8; ++nt) {
        int col = h * HD_ + nt * 16 + l;
#pragma unroll
        for (int r = 0; r < 4; ++r) {
            out[(size_t)(b * S_ + row_hi + quad * 4 + r) * HID_ + col] = ah[nt][r] * ih[r];
            out[(size_t)(b * S_ + row_lo + quad * 4 + r) * HID_ + col] = al[nt][r] * il[r];
        }
    }
}

extern "C" void kernel_launch(void* const* d_in, const int* in_sizes, int n_in,
                              void* d_out, int out_size, void* d_ws, size_t ws_size,
                              hipStream_t stream) {
    const float* hs    = (const float*)d_in[0];
    const float* amask = (const float*)d_in[1];
    const float* Wq    = (const float*)d_in[2];
    const float* bq    = (const float*)d_in[3];
    const float* Wk    = (const float*)d_in[4];
    const float* bk    = (const float*)d_in[5];
    const float* Wv    = (const float*)d_in[6];
    const float* bv    = (const float*)d_in[7];
    float* out = (float*)d_out;

    bhalf* hsb = (bhalf*)d_ws;              // 8,388,608 elems
    bhalf* wqb = hsb + 8388608;             // 3 x 4,194,304 (contiguous)
    bhalf* Qb  = wqb + 3 * 4194304;         // Q,K: 2 x 8,388,608
    bhalf* Kb  = Qb + 8388608;
    bhalf* VTb = Kb + 8388608;              // V^T written directly by qkv_gemm
    float2* tab = (float2*)(VTb + 8388608); // 65536 float2 = 512 KB

    rope_table<<<256, 256, 0, stream>>>(tab);
    cast_all<<<20480, 256, 0, stream>>>(hs, Wq, Wk, Wv, hsb);
    qkv_gemm<<<dim3(32, 16, 3), 256, 0, stream>>>(hsb, wqb, bq, bk, bv, tab, Qb, VTb);
    flash_attn<<<dim3(8, 32), 512, 0, stream>>>(Qb, Kb, VTb, amask, out);
}

// Round 7
// 461.963 us; speedup vs baseline: 4.2183x; 4.2183x over previous
//
#include <hip/hip_runtime.h>

typedef unsigned short bhalf;          // bf16 bits
typedef __attribute__((ext_vector_type(4))) float    f32x4;
typedef __attribute__((ext_vector_type(8))) short    s16x8;
typedef __attribute__((ext_vector_type(4))) float    floatx4;
typedef __attribute__((ext_vector_type(4))) unsigned short u16x4;

#define B_  2
#define S_  2048
#define HID_ 2048
#define NH_ 16
#define HD_ 128
#define M_  (B_*S_)          // 4096
#define MASKV (-10000.0f)

__device__ __forceinline__ bhalf f32_to_bf16(float f) {
    union { float f; unsigned int u; } v; v.f = f;
    unsigned int r = v.u + 0x7FFFu + ((v.u >> 16) & 1u);   // RNE
    return (bhalf)(r >> 16);
}
__device__ __forceinline__ bhalf f32_to_bf16_trunc(float f) {
    union { float f; unsigned int u; } v; v.f = f;
    return (bhalf)(v.u >> 16);
}

// async global->LDS, 16B per lane; LDS dest = wave-uniform base + lane*16
__device__ __forceinline__ void gl_lds16(const void* g, void* l) {
    __builtin_amdgcn_global_load_lds(
        (const __attribute__((address_space(1))) void*)g,
        (__attribute__((address_space(3))) void*)l, 16, 0, 0);
}

// ---------------- fused cast fp32 -> bf16 for hs + Wq + Wk + Wv ------------
__global__ __launch_bounds__(256) void cast_all(const float* __restrict__ hs,
                                                const float* __restrict__ Wq,
                                                const float* __restrict__ Wk,
                                                const float* __restrict__ Wv,
                                                bhalf* __restrict__ dst) {
    int idx = blockIdx.x * 256 + threadIdx.x;           // 0 .. 5,242,879
    const float* src;
    if (idx < 2097152)      src = hs + (size_t)idx * 4;
    else if (idx < 3145728) src = Wq + (size_t)(idx - 2097152) * 4;
    else if (idx < 4194304) src = Wk + (size_t)(idx - 3145728) * 4;
    else                    src = Wv + (size_t)(idx - 4194304) * 4;
    floatx4 f = *(const floatx4*)src;
    u16x4 o;
    o.x = f32_to_bf16(f.x); o.y = f32_to_bf16(f.y);
    o.z = f32_to_bf16(f.z); o.w = f32_to_bf16(f.w);
    *(u16x4*)(dst + (size_t)idx * 4) = o;
}

// ---------------- RoPE table -----------------------------------------------
__global__ __launch_bounds__(256) void rope_table(float2* __restrict__ tab) {
    int idx = blockIdx.x * 256 + threadIdx.x;   // 65536 = 2048 s x 32 i
    int i = idx & 31, s = idx >> 5;
    float inv = expf(-(float)i * 0.2878231366242557f);   // ln(10000)/32
    float ang = (float)s * inv;
    tab[idx] = make_float2(sinf(ang), cosf(ang));
}

// ---------------- fused QKV GEMM, BK=64, RoPE fused in epilogue ------------
// z==2 (V) writes V^T directly: VT[((b*16+h)*128+d)*2048 + s]
// z<2: wx==0 waves (cols 0..63 of each head) apply RoPE via shfl_xor pairing.
__global__ __launch_bounds__(256) void qkv_gemm(const bhalf* __restrict__ A,
                                                const bhalf* __restrict__ Wb,
                                                const float* __restrict__ bq,
                                                const float* __restrict__ bk,
                                                const float* __restrict__ bv,
                                                const float2* __restrict__ tab,
                                                bhalf* __restrict__ Out,
                                                bhalf* __restrict__ VTo) {
    __shared__ __align__(16) bhalf As[128 * 64];
    __shared__ __align__(16) bhalf Bs[128 * 64];
    const int tid  = threadIdx.x;
    const int lane = tid & 63, w = tid >> 6;
    const int wy = w >> 1, wx = w & 1;
    const int quad = lane >> 4, l = lane & 15;
    const int m0 = blockIdx.x * 128, n0 = blockIdx.y * 128;
    const int z  = blockIdx.z;
    const bhalf* W    = Wb + (size_t)z * HID_ * HID_;
    const float* bias = (z == 0) ? bq : (z == 1) ? bk : bv;
    bhalf* out        = Out + (size_t)z * M_ * HID_;

    f32x4 acc[4][4] = {};

    for (int kt = 0; kt < HID_; kt += 64) {
#pragma unroll
        for (int j = 0; j < 4; ++j) {
            int slot0 = j * 256 + w * 64;          // wave-uniform
            int slot  = slot0 + lane;
            int row = slot >> 3;
            int cg  = (slot & 7) ^ (row & 7);      // 3-bit swizzle
            gl_lds16(A + (size_t)(m0 + row) * HID_ + kt + cg * 8, As + slot0 * 8);
            gl_lds16(W + (size_t)(n0 + row) * HID_ + kt + cg * 8, Bs + slot0 * 8);
        }
        __syncthreads();
        s16x8 af[4][2], bfr[4][2];
#pragma unroll
        for (int mt = 0; mt < 4; ++mt) {
            int row = wy * 64 + mt * 16 + l;
#pragma unroll
            for (int ks = 0; ks < 2; ++ks) {
                int kk = ks * 4 + quad;
                af[mt][ks] = *(const s16x8*)(As + (row * 8 + (kk ^ (row & 7))) * 8);
            }
        }
#pragma unroll
        for (int nt = 0; nt < 4; ++nt) {
            int row = wx * 64 + nt * 16 + l;
#pragma unroll
            for (int ks = 0; ks < 2; ++ks) {
                int kk = ks * 4 + quad;
                bfr[nt][ks] = *(const s16x8*)(Bs + (row * 8 + (kk ^ (row & 7))) * 8);
            }
        }
#pragma unroll
        for (int ks = 0; ks < 2; ++ks)
#pragma unroll
            for (int mt = 0; mt < 4; ++mt)
#pragma unroll
                for (int nt = 0; nt < 4; ++nt)
                    acc[mt][nt] = __builtin_amdgcn_mfma_f32_16x16x32_bf16(
                        af[mt][ks], bfr[nt][ks], acc[mt][nt], 0, 0, 0);
        __syncthreads();
    }
    if (z == 2) {
        // V^T epilogue: pack 4 consecutive s into one 8B store
#pragma unroll
        for (int mt = 0; mt < 4; ++mt) {
#pragma unroll
            for (int nt = 0; nt < 4; ++nt) {
                int col = n0 + wx * 64 + nt * 16 + l;     // h*128 + d
                float bv_ = bias[col];
                int row0 = m0 + wy * 64 + mt * 16 + quad * 4;  // = b*2048 + s0
                int bb = row0 >> 11, s0 = row0 & 2047;
                u16x4 o;
#pragma unroll
                for (int r = 0; r < 4; ++r) o[r] = f32_to_bf16(acc[mt][nt][r] + bv_);
                *(u16x4*)(VTo + ((size_t)(bb * 16) * 128 + col) * S_ + s0) = o;
            }
        }
    } else if (wx == 0) {
        // rotary region (cols 0..63 of each head): RoPE via lane-pair exchange
#pragma unroll
        for (int mt = 0; mt < 4; ++mt) {
#pragma unroll
            for (int nt = 0; nt < 4; ++nt) {
                int col = n0 + nt * 16 + l;
                float bv_ = bias[col];
                int i = (nt * 16 + l) >> 1;                // rotary pair index
#pragma unroll
                for (int r = 0; r < 4; ++r) {
                    int row = m0 + wy * 64 + mt * 16 + quad * 4 + r;
                    float v  = acc[mt][nt][r] + bv_;
                    float vp = __shfl_xor(v, 1, 64);       // partner col^1
                    float2 sc = tab[(row & 2047) * 32 + i];
                    float y = (l & 1) ? (v * sc.y + vp * sc.x)
                                      : (v * sc.y - vp * sc.x);
                    out[(size_t)row * HID_ + col] = f32_to_bf16(y);
                }
            }
        }
    } else {
#pragma unroll
        for (int mt = 0; mt < 4; ++mt) {
#pragma unroll
            for (int nt = 0; nt < 4; ++nt) {
                int col = n0 + 64 + nt * 16 + l;
                float bv_ = bias[col];
#pragma unroll
                for (int r = 0; r < 4; ++r) {
                    int row = m0 + wy * 64 + mt * 16 + quad * 4 + r;
                    out[(size_t)row * HID_ + col] = f32_to_bf16(acc[mt][nt][r] + bv_);
                }
            }
        }
    }
}

// ---------------- flash attention (R5 proven version) ----------------------
// Block (qt, bh): hi tile = 64 rows at (31-qt)*64 (waves 0-3, 16 rows each),
//                 lo tile = 64 rows at qt*64      (waves 4-7).
// 128-key chunks; K/V double-buffered (2 x 32KB each = 128KB LDS).
// P overlays the *current* K buffer after a raw s_barrier (no vmcnt drain,
// so the in-flight next-chunk DMA is not stalled).
__global__ __launch_bounds__(512, 2) void flash_attn(const bhalf* __restrict__ Qb,
                                                     const bhalf* __restrict__ Kb,
                                                     const bhalf* __restrict__ VT,
                                                     const float* __restrict__ amask,
                                                     float* __restrict__ out) {
    __shared__ __align__(16) bhalf Kbuf[2][2048 * 8];   // 2 x 32KB
    __shared__ __align__(16) bhalf Vbuf[2][2048 * 8];   // 2 x 32KB
    const int tid = threadIdx.x, lane = tid & 63, w = tid >> 6;   // w 0..7
    const int quad = lane >> 4, l = lane & 15;
    const int qt = blockIdx.x, bh = blockIdx.y;
    const int b = bh >> 4, h = bh & 15;
    const bool is_hi = (w < 4);
    const int ws = w & 3;
    const int myrow = is_hi ? ((31 - qt) * 64 + ws * 16) : (qt * 64 + ws * 16);
    const int ch_hi   = (33 - qt) >> 1;          // chunks needed by hi tile
    const int lo_last = (qt * 64 + 63) >> 7;     // last active chunk, lo tile
    const int my_last = is_hi ? (ch_hi - 1) : lo_last;

    // Q A-fragments for my 16 rows: A[m=l][k=ks*32+quad*8+j]
    s16x8 qf[4];
    {
        const bhalf* Qrow = Qb + (size_t)(b * S_ + myrow + l) * HID_ + h * HD_;
#pragma unroll
        for (int ks = 0; ks < 4; ++ks)
            qf[ks] = *(const s16x8*)(Qrow + ks * 32 + quad * 8);
    }
    s16x8 ones;
#pragma unroll
    for (int j = 0; j < 8; ++j) ones[j] = (short)0x3F80;

    float m_run[4] = {-1e30f, -1e30f, -1e30f, -1e30f};
    f32x4 l_acc = {};
    f32x4 acc[8] = {};
    const int fpl = ((l >> 2) << 1) | (l & 1);   // fp(m=l) for P reads

    // ---- prologue: stage chunk 0 into buffer 0 ----
#pragma unroll
    for (int j = 0; j < 4; ++j) {
        int slot0 = j * 512 + w * 64;            // wave-uniform
        int slot  = slot0 + lane;
        int row = slot >> 4, x = slot & 15;
        int g   = (x & 8) | ((x ^ row) & 7);
        gl_lds16(Kb + (size_t)(b * S_ + row) * HID_ + h * HD_ + g * 8,
                 &Kbuf[0][slot0 * 8]);
        gl_lds16(VT + ((size_t)bh * HD_ + row) * S_ + g * 8,
                 &Vbuf[0][slot0 * 8]);
    }

    for (int kc = 0; kc < ch_hi; ++kc) {
        const int cur = kc & 1, nxt = cur ^ 1;
        const int key0 = kc * 128;
        __syncthreads();   // drains staging into cur; prior chunk's reads done

        const bool active = (kc <= my_last);
        const bool diag   = (kc == my_last);

        // mask row loads FIRST so their waitcnt doesn't drain the staging below
        float am[8];
        if (active) {
#pragma unroll
            for (int nt = 0; nt < 8; ++nt) am[nt] = amask[b * S_ + key0 + nt * 16 + l];
        }
        // issue next chunk's staging (into nxt) — drained at next top barrier
        if (kc + 1 < ch_hi) {
            const int key1 = key0 + 128;
#pragma unroll
            for (int j = 0; j < 4; ++j) {
                int slot0 = j * 512 + w * 64;
                int slot  = slot0 + lane;
                int row = slot >> 4, x = slot & 15;
                int g   = (x & 8) | ((x ^ row) & 7);
                gl_lds16(Kb + (size_t)(b * S_ + key1 + row) * HID_ + h * HD_ + g * 8,
                         &Kbuf[nxt][slot0 * 8]);
                gl_lds16(VT + ((size_t)bh * HD_ + row) * S_ + key1 + g * 8,
                         &Vbuf[nxt][slot0 * 8]);
            }
        }

        const bhalf* Kc = &Kbuf[cur][0];
        const bhalf* Vc = &Vbuf[cur][0];
        bhalf* Pw = &Kbuf[cur][0] + w * 2048;    // overlay, valid post-QK

        // ---- QK^T ----
        f32x4 s[8] = {};
        if (active) {
#pragma unroll
            for (int nt = 0; nt < 8; ++nt) {
                int key = nt * 16 + l;
#pragma unroll
                for (int ks = 0; ks < 4; ++ks) {
                    int dg = ks * 4 + quad;
                    int x  = (dg & 8) | ((dg ^ key) & 7);
                    s16x8 kf = *(const s16x8*)(Kc + (key * 16 + x) * 8);
                    s[nt] = __builtin_amdgcn_mfma_f32_16x16x32_bf16(qf[ks], kf, s[nt], 0, 0, 0);
                }
            }
        }
        // raw barrier: all QK reads of Kc retired (operands consumed pre-MFMA);
        // deliberately NO vmcnt drain so the nxt-buffer DMA stays in flight.
        __asm__ __volatile__("s_waitcnt lgkmcnt(0)\n\ts_barrier" ::: "memory");

        if (active) {
            // ---- softmax (online) + P write (bf16, swizzled) ----
#pragma unroll
            for (int r = 0; r < 4; ++r) {
                const int qrow = myrow + quad * 4 + r;
                float p[8];
#pragma unroll
                for (int nt = 0; nt < 8; ++nt) {
                    float v = s[nt][r] * 0.08838834764831845f;   // 1/sqrt(128)
                    if (diag) { int key = key0 + nt * 16 + l; v = (key > qrow) ? MASKV : v; }
                    p[nt] = v + am[nt];
                }
                float mx = fmaxf(fmaxf(fmaxf(p[0], p[1]), fmaxf(p[2], p[3])),
                                 fmaxf(fmaxf(p[4], p[5]), fmaxf(p[6], p[7])));
#pragma unroll
                for (int msk = 1; msk < 16; msk <<= 1) mx = fmaxf(mx, __shfl_xor(mx, msk, 64));
                float m_new = fmaxf(m_run[r], mx);
                float alpha = __expf(m_run[r] - m_new);
                m_run[r] = m_new;
                const int m  = quad * 4 + r;
                const int fm = (quad << 1) | (r & 1);
#pragma unroll
                for (int nt = 0; nt < 8; ++nt) {
                    float e = __expf(p[nt] - m_new);
                    int key = nt * 16 + l;
                    Pw[(m * 16 + ((key >> 3) ^ fm)) * 8 + (key & 7)] = f32_to_bf16_trunc(e);
                }
                l_acc[r] *= alpha;
#pragma unroll
                for (int nt = 0; nt < 8; ++nt) acc[nt][r] *= alpha;
            }
            // ---- PV + ones row-sum ----
#pragma unroll
            for (int kstep = 0; kstep < 4; ++kstep) {
                int kg = kstep * 4 + quad;
                s16x8 pf = *(const s16x8*)(Pw + (l * 16 + (kg ^ fpl)) * 8);
                l_acc = __builtin_amdgcn_mfma_f32_16x16x32_bf16(pf, ones, l_acc, 0, 0, 0);
#pragma unroll
                for (int nt = 0; nt < 8; ++nt) {
                    int d = nt * 16 + l;
                    int x = (kg & 8) | ((kg ^ d) & 7);
                    s16x8 vf = *(const s16x8*)(Vc + (d * 16 + x) * 8);
                    acc[nt] = __builtin_amdgcn_mfma_f32_16x16x32_bf16(pf, vf, acc[nt], 0, 0, 0);
                }
            }
        }
    }

    // ---- epilogue: O /= l, fp32 out (B,S,HID) ----
    float inv[4];
#pragma unroll
    for (int r = 0; r < 4; ++r) inv[r] = 1.f / l_acc[r];
#pragma unroll
    for (int nt = 0; nt < 8; ++nt) {
        int col = h * HD_ + nt * 16 + l;
#pragma unroll
        for (int r = 0; r < 4; ++r)
            out[(size_t)(b * S_ + myrow + quad * 4 + r) * HID_ + col] = acc[nt][r] * inv[r];
    }
}

extern "C" void kernel_launch(void* const* d_in, const int* in_sizes, int n_in,
                              void* d_out, int out_size, void* d_ws, size_t ws_size,
                              hipStream_t stream) {
    const float* hs    = (const float*)d_in[0];
    const float* amask = (const float*)d_in[1];
    const float* Wq    = (const float*)d_in[2];
    const float* bq    = (const float*)d_in[3];
    const float* Wk    = (const float*)d_in[4];
    const float* bk    = (const float*)d_in[5];
    const float* Wv    = (const float*)d_in[6];
    const float* bv    = (const float*)d_in[7];
    float* out = (float*)d_out;

    bhalf* hsb = (bhalf*)d_ws;              // 8,388,608 elems
    bhalf* wqb = hsb + 8388608;             // 3 x 4,194,304 (contiguous)
    bhalf* Qb  = wqb + 3 * 4194304;         // Q,K: 2 x 8,388,608
    bhalf* Kb  = Qb + 8388608;
    bhalf* VTb = Kb + 8388608;              // V^T written directly by qkv_gemm
    float2* tab = (float2*)(VTb + 8388608); // 65536 float2 = 512 KB

    rope_table<<<256, 256, 0, stream>>>(tab);
    cast_all<<<20480, 256, 0, stream>>>(hs, Wq, Wk, Wv, hsb);
    qkv_gemm<<<dim3(32, 16, 3), 256, 0, stream>>>(hsb, wqb, bq, bk, bv, tab, Qb, VTb);
    flash_attn<<<dim3(16, 32), 512, 0, stream>>>(Qb, Kb, VTb, amask, out);
}

// Round 8
// 404.451 us; speedup vs baseline: 4.8182x; 1.1422x over previous
//
#include <hip/hip_runtime.h>

typedef unsigned short bhalf;          // bf16 bits
typedef __attribute__((ext_vector_type(4))) float    f32x4;
typedef __attribute__((ext_vector_type(8))) short    s16x8;
typedef __attribute__((ext_vector_type(4))) float    floatx4;
typedef __attribute__((ext_vector_type(4))) unsigned short u16x4;

#define B_  2
#define S_  2048
#define HID_ 2048
#define NH_ 16
#define HD_ 128
#define M_  (B_*S_)          // 4096
#define MASKV (-10000.0f)

__device__ __forceinline__ bhalf f32_to_bf16(float f) {
    union { float f; unsigned int u; } v; v.f = f;
    unsigned int r = v.u + 0x7FFFu + ((v.u >> 16) & 1u);   // RNE
    return (bhalf)(r >> 16);
}
__device__ __forceinline__ bhalf f32_to_bf16_trunc(float f) {
    union { float f; unsigned int u; } v; v.f = f;
    return (bhalf)(v.u >> 16);
}

// async global->LDS, 16B per lane; LDS dest = wave-uniform base + lane*16
__device__ __forceinline__ void gl_lds16(const void* g, void* l) {
    __builtin_amdgcn_global_load_lds(
        (const __attribute__((address_space(1))) void*)g,
        (__attribute__((address_space(3))) void*)l, 16, 0, 0);
}

// ---------------- fused cast fp32 -> bf16 for hs + Wq + Wk + Wv ------------
__global__ __launch_bounds__(256) void cast_all(const float* __restrict__ hs,
                                                const float* __restrict__ Wq,
                                                const float* __restrict__ Wk,
                                                const float* __restrict__ Wv,
                                                bhalf* __restrict__ dst) {
    int idx = blockIdx.x * 256 + threadIdx.x;           // 0 .. 5,242,879
    const float* src;
    if (idx < 2097152)      src = hs + (size_t)idx * 4;
    else if (idx < 3145728) src = Wq + (size_t)(idx - 2097152) * 4;
    else if (idx < 4194304) src = Wk + (size_t)(idx - 3145728) * 4;
    else                    src = Wv + (size_t)(idx - 4194304) * 4;
    floatx4 f = *(const floatx4*)src;
    u16x4 o;
    o.x = f32_to_bf16(f.x); o.y = f32_to_bf16(f.y);
    o.z = f32_to_bf16(f.z); o.w = f32_to_bf16(f.w);
    *(u16x4*)(dst + (size_t)idx * 4) = o;
}

// ---------------- RoPE table -----------------------------------------------
__global__ __launch_bounds__(256) void rope_table(float2* __restrict__ tab) {
    int idx = blockIdx.x * 256 + threadIdx.x;   // 65536 = 2048 s x 32 i
    int i = idx & 31, s = idx >> 5;
    float inv = expf(-(float)i * 0.2878231366242557f);   // ln(10000)/32
    float ang = (float)s * inv;
    tab[idx] = make_float2(sinf(ang), cosf(ang));
}

// ---------------- fused QKV GEMM, BK=32 (R5-proven), RoPE in epilogue ------
// z==2 (V) writes V^T directly: VT[((b*16+h)*128+d)*2048 + s]
// z<2: wx==0 waves (cols 0..63 of each head) apply RoPE via shfl_xor pairing.
__global__ __launch_bounds__(256) void qkv_gemm(const bhalf* __restrict__ A,
                                                const bhalf* __restrict__ Wb,
                                                const float* __restrict__ bq,
                                                const float* __restrict__ bk,
                                                const float* __restrict__ bv,
                                                const float2* __restrict__ tab,
                                                bhalf* __restrict__ Out,
                                                bhalf* __restrict__ VTo) {
    __shared__ __align__(16) bhalf As[128 * 32];
    __shared__ __align__(16) bhalf Bs[128 * 32];
    const int tid  = threadIdx.x;
    const int lane = tid & 63, w = tid >> 6;
    const int wy = w >> 1, wx = w & 1;
    const int quad = lane >> 4, l = lane & 15;
    const int m0 = blockIdx.x * 128, n0 = blockIdx.y * 128;
    const int z  = blockIdx.z;
    const bhalf* W    = Wb + (size_t)z * HID_ * HID_;
    const float* bias = (z == 0) ? bq : (z == 1) ? bk : bv;
    bhalf* out        = Out + (size_t)z * M_ * HID_;

    f32x4 acc[4][4] = {};

    for (int kt = 0; kt < HID_; kt += 32) {
#pragma unroll
        for (int j = 0; j < 2; ++j) {
            int slot0 = j * 256 + w * 64;          // wave-uniform
            int slot  = slot0 + lane;
            int row = slot >> 2;
            int cg  = (slot & 3) ^ ((row >> 1) & 3);   // swizzle
            gl_lds16(A + (size_t)(m0 + row) * HID_ + kt + cg * 8, As + slot0 * 8);
            gl_lds16(W + (size_t)(n0 + row) * HID_ + kt + cg * 8, Bs + slot0 * 8);
        }
        __syncthreads();
        s16x8 af[4], bfr[4];
#pragma unroll
        for (int mt = 0; mt < 4; ++mt) {
            int row = wy * 64 + mt * 16 + l;
            int cgs = quad ^ ((row >> 1) & 3);
            af[mt] = *(const s16x8*)(As + (row * 4 + cgs) * 8);
        }
#pragma unroll
        for (int nt = 0; nt < 4; ++nt) {
            int row = wx * 64 + nt * 16 + l;
            int cgs = quad ^ ((row >> 1) & 3);
            bfr[nt] = *(const s16x8*)(Bs + (row * 4 + cgs) * 8);
        }
#pragma unroll
        for (int mt = 0; mt < 4; ++mt)
#pragma unroll
            for (int nt = 0; nt < 4; ++nt)
                acc[mt][nt] = __builtin_amdgcn_mfma_f32_16x16x32_bf16(
                    af[mt], bfr[nt], acc[mt][nt], 0, 0, 0);
        __syncthreads();
    }
    if (z == 2) {
        // V^T epilogue: pack 4 consecutive s into one 8B store
#pragma unroll
        for (int mt = 0; mt < 4; ++mt) {
#pragma unroll
            for (int nt = 0; nt < 4; ++nt) {
                int col = n0 + wx * 64 + nt * 16 + l;     // h*128 + d
                float bv_ = bias[col];
                int row0 = m0 + wy * 64 + mt * 16 + quad * 4;  // = b*2048 + s0
                int bb = row0 >> 11, s0 = row0 & 2047;
                u16x4 o;
#pragma unroll
                for (int r = 0; r < 4; ++r) o[r] = f32_to_bf16(acc[mt][nt][r] + bv_);
                *(u16x4*)(VTo + ((size_t)(bb * 16) * 128 + col) * S_ + s0) = o;
            }
        }
    } else if (wx == 0) {
        // rotary region (cols 0..63 of each head): RoPE via lane-pair exchange
#pragma unroll
        for (int mt = 0; mt < 4; ++mt) {
#pragma unroll
            for (int nt = 0; nt < 4; ++nt) {
                int col = n0 + nt * 16 + l;
                float bv_ = bias[col];
                int i = (nt * 16 + l) >> 1;                // rotary pair index
#pragma unroll
                for (int r = 0; r < 4; ++r) {
                    int row = m0 + wy * 64 + mt * 16 + quad * 4 + r;
                    float v  = acc[mt][nt][r] + bv_;
                    float vp = __shfl_xor(v, 1, 64);       // partner col^1
                    float2 sc = tab[(row & 2047) * 32 + i];
                    float y = (l & 1) ? (v * sc.y + vp * sc.x)
                                      : (v * sc.y - vp * sc.x);
                    out[(size_t)row * HID_ + col] = f32_to_bf16(y);
                }
            }
        }
    } else {
#pragma unroll
        for (int mt = 0; mt < 4; ++mt) {
#pragma unroll
            for (int nt = 0; nt < 4; ++nt) {
                int col = n0 + 64 + nt * 16 + l;
                float bv_ = bias[col];
#pragma unroll
                for (int r = 0; r < 4; ++r) {
                    int row = m0 + wy * 64 + mt * 16 + quad * 4 + r;
                    out[(size_t)row * HID_ + col] = f32_to_bf16(acc[mt][nt][r] + bv_);
                }
            }
        }
    }
}

// ---------------- flash attention v4: 32 q-rows/wave, single tile/block ----
// 256 thr = 4 waves; wave w owns rows q0+w*32 (2 m-tiles of 16). Block handles
// ONE 128-row q-tile (tq scrambled for load balance), loops tq+1 key-chunks of
// 128. LDS 64 KB: Ks 32 + Vs 32; P (4 KB/wave) overlays Ks keys 0..63 after
// QK pass 0 (wave-private across both passes). Every kf/vf read feeds 2 MFMAs.
__device__ __forceinline__ void softmax2(f32x4 (*sc)[4], float (*m_run)[4],
        f32x4* l_acc, f32x4* ao, bhalf* Pw, int qbase, bool diag, int keybase,
        const float* am4, int quad, int l) {
#pragma unroll
    for (int mt = 0; mt < 2; ++mt) {
#pragma unroll
        for (int r = 0; r < 4; ++r) {
            const int row16 = quad * 4 + r;
            const int qrow = qbase + mt * 16 + row16;
            float p[4];
#pragma unroll
            for (int nt = 0; nt < 4; ++nt) {
                float v = sc[mt][nt][r] * 0.08838834764831845f;   // 1/sqrt(128)
                if (diag) { int key = keybase + nt * 16 + l; v = (key > qrow) ? MASKV : v; }
                p[nt] = v + am4[nt];
            }
            float mx = fmaxf(fmaxf(p[0], p[1]), fmaxf(p[2], p[3]));
#pragma unroll
            for (int msk = 1; msk < 16; msk <<= 1) mx = fmaxf(mx, __shfl_xor(mx, msk, 64));
            float m_new = fmaxf(m_run[mt][r], mx);
            float alpha = __expf(m_run[mt][r] - m_new);
            m_run[mt][r] = m_new;
            const int prow = mt * 16 + row16;
            const int fm = row16 & 7;
#pragma unroll
            for (int nt = 0; nt < 4; ++nt) {
                float e = __expf(p[nt] - m_new);
                int kl = nt * 16 + l;                      // local key 0..63
                Pw[(prow * 8 + ((kl >> 3) ^ fm)) * 8 + (kl & 7)] = f32_to_bf16_trunc(e);
            }
            l_acc[mt][r] *= alpha;
#pragma unroll
            for (int nt = 0; nt < 8; ++nt) ao[mt * 8 + nt][r] *= alpha;
        }
    }
}

__global__ __launch_bounds__(256, 2) void flash_attn(const bhalf* __restrict__ Qb,
                                                     const bhalf* __restrict__ Kb,
                                                     const bhalf* __restrict__ VT,
                                                     const float* __restrict__ amask,
                                                     float* __restrict__ out) {
    __shared__ __align__(16) bhalf Ks[2048 * 8];    // 32 KB: 128 keys x 16 dgrp
    __shared__ __align__(16) bhalf Vs[2048 * 8];    // 32 KB: 128 d x 16 kgrp
    const int tid = threadIdx.x, lane = tid & 63, w = tid >> 6;   // w 0..3
    const int quad = lane >> 4, l = lane & 15;
    const int x = blockIdx.x, bh = blockIdx.y;
    const int b = bh >> 4, h = bh & 15;
    // tile scramble: bitrev(x) ^ (bh-bit4 ? 15 : 0) — complements pair on a CU
    int tq = (((x & 1) << 3) | ((x & 2) << 1) | ((x & 4) >> 1) | ((x & 8) >> 3))
             ^ ((bh & 16) ? 15 : 0);
    const int q0 = tq * 128 + w * 32;               // wave's 32 rows
    const int nch = tq + 1;

    // Q A-fragments, 2 m-tiles: A[m=l][k=ks*32+quad*8+j]
    s16x8 qf[2][4];
#pragma unroll
    for (int mt = 0; mt < 2; ++mt) {
        const bhalf* Qrow = Qb + (size_t)(b * S_ + q0 + mt * 16 + l) * HID_ + h * HD_;
#pragma unroll
        for (int ks = 0; ks < 4; ++ks)
            qf[mt][ks] = *(const s16x8*)(Qrow + ks * 32 + quad * 8);
    }
    s16x8 ones;
#pragma unroll
    for (int j = 0; j < 8; ++j) ones[j] = (short)0x3F80;

    float m_run[2][4];
#pragma unroll
    for (int mt = 0; mt < 2; ++mt)
#pragma unroll
        for (int r = 0; r < 4; ++r) m_run[mt][r] = -1e30f;
    f32x4 l_acc[2] = {};
    f32x4 ao[16] = {};                              // [mt*8 + d-tile]
    bhalf* Pw = Ks + w * 2048;                      // overlay on Ks keys 0..63

    for (int kc = 0; kc < nch; ++kc) {
        const int key0 = kc * 128;
        __syncthreads();                             // prev chunk reads done
        float am[8];
#pragma unroll
        for (int nt = 0; nt < 8; ++nt) am[nt] = amask[b * S_ + key0 + nt * 16 + l];
        // stage K (128x128) then V^T (128x128), swizzled; 8+8 gl_lds/thread
#pragma unroll
        for (int j = 0; j < 8; ++j) {
            int slot0 = j * 256 + w * 64;            // wave-uniform
            int slot  = slot0 + lane;
            int row = slot >> 4, x16 = slot & 15;
            int g   = (x16 & 8) | ((x16 ^ row) & 7);
            gl_lds16(Kb + (size_t)(b * S_ + key0 + row) * HID_ + h * HD_ + g * 8,
                     Ks + slot0 * 8);
        }
#pragma unroll
        for (int j = 0; j < 8; ++j) {
            int slot0 = j * 256 + w * 64;
            int slot  = slot0 + lane;
            int d = slot >> 4, x16 = slot & 15;
            int g = (x16 & 8) | ((x16 ^ d) & 7);
            gl_lds16(VT + ((size_t)bh * HD_ + d) * S_ + key0 + g * 8,
                     Vs + slot0 * 8);
        }
        // K (+am) resident; V may still be in flight
        __asm__ __volatile__("s_waitcnt vmcnt(8)\n\ts_barrier" ::: "memory");

        const bool diag = (kc == tq);

        // ======== pass 0: keys key0 .. key0+63 ========
        f32x4 sc[2][4] = {};
#pragma unroll
        for (int nt = 0; nt < 4; ++nt) {
            int key = nt * 16 + l;
#pragma unroll
            for (int ks = 0; ks < 4; ++ks) {
                int dg = ks * 4 + quad;
                int xk = (dg & 8) | ((dg ^ key) & 7);
                s16x8 kf = *(const s16x8*)(Ks + (key * 16 + xk) * 8);
                sc[0][nt] = __builtin_amdgcn_mfma_f32_16x16x32_bf16(qf[0][ks], kf, sc[0][nt], 0, 0, 0);
                sc[1][nt] = __builtin_amdgcn_mfma_f32_16x16x32_bf16(qf[1][ks], kf, sc[1][nt], 0, 0, 0);
            }
        }
        // all waves done reading Ks keys 0..63 -> P may overlay
        __asm__ __volatile__("s_waitcnt lgkmcnt(0)\n\ts_barrier" ::: "memory");
        softmax2(sc, m_run, l_acc, ao, Pw, q0, diag, key0, am, quad, l);
        // V resident before first PV (block-wide)
        __asm__ __volatile__("s_waitcnt vmcnt(0)\n\ts_barrier" ::: "memory");
#pragma unroll
        for (int ks2 = 0; ks2 < 2; ++ks2) {
            s16x8 pf[2];
#pragma unroll
            for (int mt = 0; mt < 2; ++mt) {
                int rr = mt * 16 + l;
                pf[mt] = *(const s16x8*)(Pw + (rr * 8 + ((ks2 * 4 + quad) ^ (l & 7))) * 8);
                l_acc[mt] = __builtin_amdgcn_mfma_f32_16x16x32_bf16(pf[mt], ones, l_acc[mt], 0, 0, 0);
            }
#pragma unroll
            for (int nt = 0; nt < 8; ++nt) {
                int d = nt * 16 + l;
                int kg = ks2 * 4 + quad;                 // pass 0
                int xv = (kg & 8) | ((kg ^ d) & 7);
                s16x8 vf = *(const s16x8*)(Vs + (d * 16 + xv) * 8);
                ao[nt]     = __builtin_amdgcn_mfma_f32_16x16x32_bf16(pf[0], vf, ao[nt], 0, 0, 0);
                ao[8 + nt] = __builtin_amdgcn_mfma_f32_16x16x32_bf16(pf[1], vf, ao[8 + nt], 0, 0, 0);
            }
        }

        // ======== pass 1: keys key0+64 .. key0+127 (Ks upper intact) ========
        f32x4 sc1[2][4] = {};
#pragma unroll
        for (int nt = 0; nt < 4; ++nt) {
            int key = 64 + nt * 16 + l;
#pragma unroll
            for (int ks = 0; ks < 4; ++ks) {
                int dg = ks * 4 + quad;
                int xk = (dg & 8) | ((dg ^ key) & 7);
                s16x8 kf = *(const s16x8*)(Ks + (key * 16 + xk) * 8);
                sc1[0][nt] = __builtin_amdgcn_mfma_f32_16x16x32_bf16(qf[0][ks], kf, sc1[0][nt], 0, 0, 0);
                sc1[1][nt] = __builtin_amdgcn_mfma_f32_16x16x32_bf16(qf[1][ks], kf, sc1[1][nt], 0, 0, 0);
            }
        }
        // P region is wave-private: safe to rewrite without a barrier
        softmax2(sc1, m_run, l_acc, ao, Pw, q0, diag, key0 + 64, am + 4, quad, l);
#pragma unroll
        for (int ks2 = 0; ks2 < 2; ++ks2) {
            s16x8 pf[2];
#pragma unroll
            for (int mt = 0; mt < 2; ++mt) {
                int rr = mt * 16 + l;
                pf[mt] = *(const s16x8*)(Pw + (rr * 8 + ((ks2 * 4 + quad) ^ (l & 7))) * 8);
                l_acc[mt] = __builtin_amdgcn_mfma_f32_16x16x32_bf16(pf[mt], ones, l_acc[mt], 0, 0, 0);
            }
#pragma unroll
            for (int nt = 0; nt < 8; ++nt) {
                int d = nt * 16 + l;
                int kg = 8 + ks2 * 4 + quad;             // pass 1
                int xv = (kg & 8) | ((kg ^ d) & 7);
                s16x8 vf = *(const s16x8*)(Vs + (d * 16 + xv) * 8);
                ao[nt]     = __builtin_amdgcn_mfma_f32_16x16x32_bf16(pf[0], vf, ao[nt], 0, 0, 0);
                ao[8 + nt] = __builtin_amdgcn_mfma_f32_16x16x32_bf16(pf[1], vf, ao[8 + nt], 0, 0, 0);
            }
        }
    }

    // ---- epilogue: O /= l, fp32 out (B,S,HID) ----
#pragma unroll
    for (int mt = 0; mt < 2; ++mt) {
        float inv[4];
#pragma unroll
        for (int r = 0; r < 4; ++r) inv[r] = 1.f / l_acc[mt][r];
#pragma unroll
        for (int nt = 0; nt < 8; ++nt) {
            int col = h * HD_ + nt * 16 + l;
#pragma unroll
            for (int r = 0; r < 4; ++r) {
                int row = b * S_ + q0 + mt * 16 + quad * 4 + r;
                out[(size_t)row * HID_ + col] = ao[mt * 8 + nt][r] * inv[r];
            }
        }
    }
}

extern "C" void kernel_launch(void* const* d_in, const int* in_sizes, int n_in,
                              void* d_out, int out_size, void* d_ws, size_t ws_size,
                              hipStream_t stream) {
    const float* hs    = (const float*)d_in[0];
    const float* amask = (const float*)d_in[1];
    const float* Wq    = (const float*)d_in[2];
    const float* bq    = (const float*)d_in[3];
    const float* Wk    = (const float*)d_in[4];
    const float* bk    = (const float*)d_in[5];
    const float* Wv    = (const float*)d_in[6];
    const float* bv    = (const float*)d_in[7];
    float* out = (float*)d_out;

    bhalf* hsb = (bhalf*)d_ws;              // 8,388,608 elems
    bhalf* wqb = hsb + 8388608;             // 3 x 4,194,304 (contiguous)
    bhalf* Qb  = wqb + 3 * 4194304;         // Q,K: 2 x 8,388,608
    bhalf* Kb  = Qb + 8388608;
    bhalf* VTb = Kb + 8388608;              // V^T written directly by qkv_gemm
    float2* tab = (float2*)(VTb + 8388608); // 65536 float2 = 512 KB

    rope_table<<<256, 256, 0, stream>>>(tab);
    cast_all<<<20480, 256, 0, stream>>>(hs, Wq, Wk, Wv, hsb);
    qkv_gemm<<<dim3(32, 16, 3), 256, 0, stream>>>(hsb, wqb, bq, bk, bv, tab, Qb, VTb);
    flash_attn<<<dim3(16, 32), 256, 0, stream>>>(Qb, Kb, VTb, amask, out);
}